// Round 7
// baseline (238.440 us; speedup 1.0000x reference)
//
#include <hip/hip_runtime.h>

#define N 8192
#define M 4
#define L 256

// ws layout (float offsets)
#define WS_SE   0              // [5][N] rank-scattered exp(hazard) — bijective plain stores
#define WS_RANK (5 * N)        // [N]    int ranks (strict-less count)
#define WS_KM   (6 * N)        // [0,1024) modality KL partials, [1024,2048) joint

#define RNKBLK 1024            // rank blocks: 8 elements each, 32 lanes per element
#define KLB 1024               // KL streaming blocks
#define GRID_A (RNKBLK + KLB)  // 2048 blocks * 4 waves = exactly 32 waves/CU, all resident

__device__ __forceinline__ float waveSum(float v) {
#pragma unroll
    for (int off = 32; off > 0; off >>= 1) v += __shfl_down(v, off, 64);
    return v;
}

__device__ __forceinline__ float kl4(float4 l, float4 s) {
    float k;
    k  = 0.5f * (s.x * s.x + l.x * l.x) - __logf(s.x) - 0.5f;
    k += 0.5f * (s.y * s.y + l.y * l.y) - __logf(s.y) - 0.5f;
    k += 0.5f * (s.z * s.z + l.z * l.z) - __logf(s.z) - 0.5f;
    k += 0.5f * (s.w * s.w + l.w * l.w) - __logf(s.w) - 0.5f;
    return k;
}

// ---- kernel A: rank+scatter (1024 blocks) ∥ ALL KL streaming (1024 blocks) ----
__global__ __launch_bounds__(256) void kernelA(
    const float* __restrict__ jlh, const float* __restrict__ mlh,
    const float4* __restrict__ jloc4, const float4* __restrict__ jscale4,
    const float4* __restrict__ mloc4, const float4* __restrict__ mscale4,
    const float* __restrict__ target, float* __restrict__ ws)
{
    __shared__ float red[8];         // KL reduction only — no LDS tax
    const int tid = threadIdx.x, bid = blockIdx.x;

    if ((bid & 1) == 0) {
        // ================= rank + scatter =================
        // 8 elements/block, 32 lanes/element. Lanes scan target directly:
        // tg4[q] = {t_{2q}, ev_{2q}, t_{2q+1}, ev_{2q+1}} — 2 times per float4.
        const int rb  = bid >> 1;                     // 0..1023
        const int e   = rb * 8 + (tid >> 5);
        const int sub = tid & 31;
        const float ti = target[2 * e];
        const float4* __restrict__ tg4 = (const float4*)target;

        int rlt = 0, req = 0;
#pragma unroll 8
        for (int k = 0; k < 128; ++k) {
            const float4 f = tg4[sub + 32 * k];       // coalesced: 32 lanes = 512 B
            rlt += (f.x < ti)  ? 1 : 0;
            rlt += (f.z < ti)  ? 1 : 0;
            req += (f.x == ti) ? 1 : 0;
            req += (f.z == ti) ? 1 : 0;
        }
        // butterfly over the 32-lane group (masks <32 stay within wave half)
        rlt += __shfl_xor(rlt, 1, 64); rlt += __shfl_xor(rlt, 2, 64);
        rlt += __shfl_xor(rlt, 4, 64); rlt += __shfl_xor(rlt, 8, 64);
        rlt += __shfl_xor(rlt, 16, 64);
        req += __shfl_xor(req, 1, 64); req += __shfl_xor(req, 2, 64);
        req += __shfl_xor(req, 4, 64); req += __shfl_xor(req, 8, 64);
        req += __shfl_xor(req, 16, 64);

        int slot = rlt;                // unique when no ties (req counts self)
        if (req > 1) {                 // rare, group-uniform: stable offset among ties
            int eql = 0;
            for (int k = 0; k < 128; ++k) {
                const int q = sub + 32 * k;
                const float4 f = tg4[q];
                eql += (f.x == ti && (2 * q)     < e) ? 1 : 0;
                eql += (f.z == ti && (2 * q + 1) < e) ? 1 : 0;
            }
            eql += __shfl_xor(eql, 1, 64); eql += __shfl_xor(eql, 2, 64);
            eql += __shfl_xor(eql, 4, 64); eql += __shfl_xor(eql, 8, 64);
            eql += __shfl_xor(eql, 16, 64);
            slot = rlt + eql;          // stable rank: bijection even with ties
        }

        if (sub == 0) ((int*)ws)[WS_RANK + e] = rlt;
        if (sub < 5) {                 // scatter exp(hazard) with plain stores
            const float h = (sub == 0) ? jlh[e] : mlh[(sub - 1) * N + e];
            ws[WS_SE + sub * N + slot] = __expf(h);
        }
    } else {
        // ================= KL streaming (all 80 MB) =================
        const int kb = bid >> 1;                      // 0..1023
        float km = 0.f, kj = 0.f;
#pragma unroll
        for (int it = 0; it < 8; ++it) {              // modality: 2048 f4-pairs/block
            const int idx = kb * 2048 + it * 256 + tid;
            km += kl4(mloc4[idx], mscale4[idx]);
        }
#pragma unroll
        for (int it = 0; it < 2; ++it) {              // joint: 512 f4-pairs/block
            const int idx = kb * 512 + it * 256 + tid;
            kj += kl4(jloc4[idx], jscale4[idx]);
        }
        km = waveSum(km);
        kj = waveSum(kj);
        const int lane = tid & 63, w = tid >> 6;
        if (lane == 0) { red[w] = km; red[4 + w] = kj; }
        __syncthreads();
        if (tid == 0) ws[WS_KM + kb]        = red[0] + red[1] + red[2] + red[3];
        if (tid == 1) ws[WS_KM + 1024 + kb] = red[4] + red[5] + red[6] + red[7];
    }
}

// ---- kernel C: suffix-scan (in LDS) + gather + epilogue + combine ----
__global__ __launch_bounds__(1024) void kernelC(
    const float* __restrict__ jlh, const float* __restrict__ mlh,
    const float* __restrict__ target, const float* __restrict__ alpha_p,
    const float* __restrict__ beta_p, float* __restrict__ ws,
    float* __restrict__ out)
{
    __shared__ float suf[N];         // 32 KB suffix table for the current stream
    __shared__ float wt[16];
    __shared__ float red[16][8];

    const int tid = threadIdx.x;
    const int lane = tid & 63, w = tid >> 6;

    // per-thread metadata: 8 contiguous elements
    int   rk[8];
    float ev[8];
#pragma unroll
    for (int k = 0; k < 8; ++k) {
        const int i = tid * 8 + k;
        rk[k] = ((const int*)ws)[WS_RANK + i];
        ev[k] = target[2 * i + 1];
    }
    float evs = 0.f;
#pragma unroll
    for (int k = 0; k < 8; ++k) evs += ev[k];

    float c[5];
#pragma unroll
    for (int s = 0; s < 5; ++s) c[s] = 0.f;

    for (int s = 0; s < 5; ++s) {
        // load this stream's sortedE slice, local inclusive suffix over 8 elems
        const float4* __restrict__ src4 = (const float4*)(ws + WS_SE + s * N);
        const float4 a = src4[tid * 2], b = src4[tid * 2 + 1];
        float v[8];
        v[0] = a.x; v[1] = a.y; v[2] = a.z; v[3] = a.w;
        v[4] = b.x; v[5] = b.y; v[6] = b.z; v[7] = b.w;
#pragma unroll
        for (int k = 6; k >= 0; --k) v[k] += v[k + 1];
        const float T = v[0];
        // wave-level inclusive suffix of per-thread totals
        float x = T;
#pragma unroll
        for (int off = 1; off < 64; off <<= 1) {
            const float y = __shfl_down(x, off, 64);
            if (lane + off < 64) x += y;
        }
        __syncthreads();                 // all gathers of previous stream done
        if (lane == 0) wt[w] = x;        // wave totals
        __syncthreads();
        float offw = 0.f;
        for (int ww = w + 1; ww < 16; ++ww) offw += wt[ww];
        const float excl = offw + (x - T);   // strictly-later threads
#pragma unroll
        for (int k = 0; k < 8; ++k) suf[tid * 8 + k] = excl + v[k];
        __syncthreads();

        // gather + cox partial for this stream
        float cs = 0.f;
#pragma unroll
        for (int k = 0; k < 8; ++k) {
            const int i = tid * 8 + k;
            const float h = (s == 0) ? jlh[i] : mlh[(s - 1) * N + i];
            cs += ev[k] * (h - __logf(suf[rk[k]]));
        }
        c[s] = cs;
    }

    // KL partials (2048 floats, one each for tid<1024)
    const float km = ws[WS_KM + tid];
    const float kj = ws[WS_KM + 1024 + tid];

    float vals[8] = {c[0], c[1], c[2], c[3], c[4], evs, km, kj};
#pragma unroll
    for (int q = 0; q < 8; ++q) {
        vals[q] = waveSum(vals[q]);
        if (lane == 0) red[w][q] = vals[q];
    }
    __syncthreads();
    if (tid == 0) {
        float t[8];
#pragma unroll
        for (int q = 0; q < 8; ++q) {
            float xx = 0.f;
            for (int ww = 0; ww < 16; ++ww) xx += red[ww][q];
            t[q] = xx;
        }
        const float EV = t[5];
        const float alpha = alpha_p[0], beta = beta_p[0];
        const float cox_j = -t[0] / EV;
        const float cox_m = -(t[1] + t[2] + t[3] + t[4]) / EV;
        out[0] = cox_j + beta * (t[7] / (float)N) + alpha * (cox_m + beta * (t[6] / (float)N));
    }
}

extern "C" void kernel_launch(void* const* d_in, const int* in_sizes, int n_in,
                              void* d_out, int out_size, void* d_ws, size_t ws_size,
                              hipStream_t stream) {
    const float* jlh    = (const float*)d_in[0];  // (N,)
    const float* mlh    = (const float*)d_in[1];  // (M,N)
    const float* jloc   = (const float*)d_in[2];  // (N,L)
    const float* jscale = (const float*)d_in[3];  // (N,L)
    const float* mloc   = (const float*)d_in[4];  // (M,N,L)
    const float* mscale = (const float*)d_in[5];  // (M,N,L)
    const float* target = (const float*)d_in[6];  // (N,2)
    const float* alpha  = (const float*)d_in[7];
    const float* beta   = (const float*)d_in[8];
    float* out = (float*)d_out;
    float* ws  = (float*)d_ws;

    kernelA<<<GRID_A, 256, 0, stream>>>(
        jlh, mlh, (const float4*)jloc, (const float4*)jscale,
        (const float4*)mloc, (const float4*)mscale, target, ws);
    kernelC<<<1, 1024, 0, stream>>>(jlh, mlh, target, alpha, beta, ws, out);
}